// Round 1
// baseline (153.163 us; speedup 1.0000x reference)
//
#include <hip/hip_runtime.h>
#include <stdint.h>

#define BATCH 16
#define NPTS 4096
#define DIM 384
#define NTOK (2*NPTS)
#define F4PT (DIM/4)   // 96 float4 groups per token

// Exact port of the reference Skilling transform (bits=8, ndim=3).
__device__ __forceinline__ uint32_t hilbert3(uint32_t x0, uint32_t x1, uint32_t x2) {
    #pragma unroll
    for (uint32_t q = 128; q > 1; q >>= 1) {
        uint32_t pm = q - 1;
        if (x0 & q) x0 ^= pm;
        uint32_t t = (x0 ^ x1) & pm;
        if (x1 & q) { x0 ^= pm; } else { x0 ^= t; x1 ^= t; }
        t = (x0 ^ x2) & pm;
        if (x2 & q) { x0 ^= pm; } else { x0 ^= t; x2 ^= t; }
    }
    x1 ^= x0;
    x2 ^= x1;
    uint32_t t = 0;
    #pragma unroll
    for (uint32_t q = 128; q > 1; q >>= 1) { if (x2 & q) t ^= (q - 1); }
    x0 ^= t; x1 ^= t; x2 ^= t;
    uint32_t h = 0;
    #pragma unroll
    for (int bp = 7; bp >= 0; --bp) {
        h = (h << 1) | ((x0 >> bp) & 1u);
        h = (h << 1) | ((x1 >> bp) & 1u);
        h = (h << 1) | ((x2 >> bp) & 1u);
    }
    return h;
}

// One block per (batch, variant). Computes per-batch min/max, quantizes,
// Hilbert codes, and does a stable sort (key = code<<16 | idx) via bitonic
// sort of uint64 keys in LDS. Writes order[(b*2+v)*NPTS + n].
__global__ __launch_bounds__(256) void order_kernel(const float* __restrict__ x,
                                                    int* __restrict__ order) {
    const int b = blockIdx.x >> 1;
    const int v = blockIdx.x & 1;
    const int tid = threadIdx.x;

    __shared__ unsigned long long keys[NPTS];
    __shared__ float red[24];

    const float* xb = x + (size_t)b * NPTS * 3;

    float mnx = 1e30f, mny = 1e30f, mnz = 1e30f;
    float mxx = -1e30f, mxy = -1e30f, mxz = -1e30f;
    #pragma unroll 4
    for (int k = 0; k < 16; ++k) {
        int n = tid + k * 256;
        float px = xb[n*3+0], py = xb[n*3+1], pz = xb[n*3+2];
        mnx = fminf(mnx, px); mxx = fmaxf(mxx, px);
        mny = fminf(mny, py); mxy = fmaxf(mxy, py);
        mnz = fminf(mnz, pz); mxz = fmaxf(mxz, pz);
    }
    #pragma unroll
    for (int off = 32; off > 0; off >>= 1) {
        mnx = fminf(mnx, __shfl_xor(mnx, off));
        mny = fminf(mny, __shfl_xor(mny, off));
        mnz = fminf(mnz, __shfl_xor(mnz, off));
        mxx = fmaxf(mxx, __shfl_xor(mxx, off));
        mxy = fmaxf(mxy, __shfl_xor(mxy, off));
        mxz = fmaxf(mxz, __shfl_xor(mxz, off));
    }
    int wave = tid >> 6;
    if ((tid & 63) == 0) {
        red[wave*6+0] = mnx; red[wave*6+1] = mny; red[wave*6+2] = mnz;
        red[wave*6+3] = mxx; red[wave*6+4] = mxy; red[wave*6+5] = mxz;
    }
    __syncthreads();
    if (tid == 0) {
        for (int w = 1; w < 4; ++w) {
            mnx = fminf(mnx, red[w*6+0]); mny = fminf(mny, red[w*6+1]);
            mnz = fminf(mnz, red[w*6+2]); mxx = fmaxf(mxx, red[w*6+3]);
            mxy = fmaxf(mxy, red[w*6+4]); mxz = fmaxf(mxz, red[w*6+5]);
        }
        red[0] = mnx; red[1] = mny; red[2] = mnz;
        red[3] = mxx; red[4] = mxy; red[5] = mxz;
    }
    __syncthreads();
    mnx = red[0]; mny = red[1]; mnz = red[2];
    const float spx = fmaxf(red[3] - mnx, 1e-6f);
    const float spy = fmaxf(red[4] - mny, 1e-6f);
    const float spz = fmaxf(red[5] - mnz, 1e-6f);

    // quantize + code (op order matches reference: sub, div, mul255, clip, trunc)
    for (int k = 0; k < 16; ++k) {
        int n = tid + k * 256;
        float px = xb[n*3+0], py = xb[n*3+1], pz = xb[n*3+2];
        float gx = fminf(fmaxf(((px - mnx) / spx) * 255.0f, 0.0f), 255.0f);
        float gy = fminf(fmaxf(((py - mny) / spy) * 255.0f, 0.0f), 255.0f);
        float gz = fminf(fmaxf(((pz - mnz) / spz) * 255.0f, 0.0f), 255.0f);
        uint32_t ix = (uint32_t)(int)gx;
        uint32_t iy = (uint32_t)(int)gy;
        uint32_t iz = (uint32_t)(int)gz;
        uint32_t a0 = v ? iz : ix;
        uint32_t a2 = v ? ix : iz;
        uint32_t code = hilbert3(a0, iy, a2);
        keys[n] = ((unsigned long long)code << 16) | (unsigned long long)n;
    }
    __syncthreads();

    // bitonic sort ascending, 4096 elems
    for (int k = 2; k <= NPTS; k <<= 1) {
        for (int j = k >> 1; j > 0; j >>= 1) {
            #pragma unroll 4
            for (int s = 0; s < 16; ++s) {
                int i = tid + s * 256;
                int ixj = i ^ j;
                if (ixj > i) {
                    unsigned long long a = keys[i];
                    unsigned long long c = keys[ixj];
                    bool up = ((i & k) == 0);
                    if ((a > c) == up) { keys[i] = c; keys[ixj] = a; }
                }
            }
            __syncthreads();
        }
    }

    int* ob = order + ((b << 1) | v) * NPTS;
    #pragma unroll 4
    for (int s = 0; s < 16; ++s) {
        int n = tid + s * 256;
        ob[n] = (int)(keys[n] & 0xFFFFull);
    }
}

// Grid-stride over float4 output groups. out[b][nn][d] with nn<4096 -> variant h,
// nn>=4096 -> variant t (order_t). Coeffs staged in LDS.
__global__ __launch_bounds__(256) void token_kernel(const float* __restrict__ x,
                                                    const float* __restrict__ W,
                                                    const float* __restrict__ bias,
                                                    const float* __restrict__ gamma,
                                                    const float* __restrict__ beta,
                                                    const int* __restrict__ order,
                                                    float* __restrict__ out) {
    __shared__ __align__(16) float sW0[2][DIM];
    __shared__ __align__(16) float sW1[2][DIM];
    __shared__ __align__(16) float sW2[2][DIM];
    __shared__ __align__(16) float sC[2][DIM];
    for (int i = threadIdx.x; i < 2 * DIM; i += 256) {
        int v = i / DIM;
        int d = i - v * DIM;
        float g = gamma[i];
        sW0[v][d] = g * W[d*3+0];
        sW1[v][d] = g * W[d*3+1];
        sW2[v][d] = g * W[d*3+2];
        sC[v][d]  = g * bias[d] + beta[i];
    }
    __syncthreads();

    const int total = BATCH * NTOK * F4PT;   // 12,582,912
    const int stride = gridDim.x * blockDim.x;
    for (int g4 = blockIdx.x * blockDim.x + threadIdx.x; g4 < total; g4 += stride) {
        int token = g4 / F4PT;
        int grp = g4 - token * F4PT;
        int b = token >> 13;           // / NTOK
        int nn = token & (NTOK - 1);
        int v = nn >> 12;              // / NPTS
        int n = nn & (NPTS - 1);
        int idx = order[(((b << 1) | v) << 12) + n];
        const float* p = x + (size_t)(b * NPTS + idx) * 3;
        float px = p[0], py = p[1], pz = p[2];
        int d0 = grp << 2;
        float4 w0 = *(const float4*)&sW0[v][d0];
        float4 w1 = *(const float4*)&sW1[v][d0];
        float4 w2 = *(const float4*)&sW2[v][d0];
        float4 c  = *(const float4*)&sC[v][d0];
        float4 o;
        o.x = px*w0.x + py*w1.x + pz*w2.x + c.x;
        o.y = px*w0.y + py*w1.y + pz*w2.y + c.y;
        o.z = px*w0.z + py*w1.z + pz*w2.z + c.z;
        o.w = px*w0.w + py*w1.w + pz*w2.w + c.w;
        reinterpret_cast<float4*>(out)[g4] = o;
    }
}

extern "C" void kernel_launch(void* const* d_in, const int* in_sizes, int n_in,
                              void* d_out, int out_size, void* d_ws, size_t ws_size,
                              hipStream_t stream) {
    const float* x     = (const float*)d_in[0];
    const float* W     = (const float*)d_in[1];
    const float* bias  = (const float*)d_in[2];
    const float* gamma = (const float*)d_in[3];
    const float* beta  = (const float*)d_in[4];
    int* order = (int*)d_ws;   // 16*2*4096 int32 = 512 KB

    hipLaunchKernelGGL(order_kernel, dim3(BATCH * 2), dim3(256), 0, stream, x, order);
    hipLaunchKernelGGL(token_kernel, dim3(2048), dim3(256), 0, stream,
                       x, W, bias, gamma, beta, order, (float*)d_out);
}

// Round 2
// 86.476 us; speedup vs baseline: 1.7712x; 1.7712x over previous
//
#include <hip/hip_runtime.h>
#include <stdint.h>

#define BATCH 16
#define NPTS 4096
#define DIM 384
#define NTOK (2*NPTS)
#define F4PT (DIM/4)   // 96 float4 groups per token

typedef unsigned long long u64;

// Exact port of the reference Skilling transform (bits=8, ndim=3).
__device__ __forceinline__ uint32_t hilbert3(uint32_t x0, uint32_t x1, uint32_t x2) {
    #pragma unroll
    for (uint32_t q = 128; q > 1; q >>= 1) {
        uint32_t pm = q - 1;
        if (x0 & q) x0 ^= pm;
        uint32_t t = (x0 ^ x1) & pm;
        if (x1 & q) { x0 ^= pm; } else { x0 ^= t; x1 ^= t; }
        t = (x0 ^ x2) & pm;
        if (x2 & q) { x0 ^= pm; } else { x0 ^= t; x2 ^= t; }
    }
    x1 ^= x0;
    x2 ^= x1;
    uint32_t t = 0;
    #pragma unroll
    for (uint32_t q = 128; q > 1; q >>= 1) { if (x2 & q) t ^= (q - 1); }
    x0 ^= t; x1 ^= t; x2 ^= t;
    uint32_t h = 0;
    #pragma unroll
    for (int bp = 7; bp >= 0; --bp) {
        h = (h << 1) | ((x0 >> bp) & 1u);
        h = (h << 1) | ((x1 >> bp) & 1u);
        h = (h << 1) | ((x2 >> bp) & 1u);
    }
    return h;
}

__device__ __forceinline__ u64 shflx64(u64 v, int mask) {
    int lo = __shfl_xor((int)(uint32_t)v, mask);
    int hi = __shfl_xor((int)(uint32_t)(v >> 32), mask);
    return ((u64)(uint32_t)hi << 32) | (uint32_t)lo;
}

__device__ __forceinline__ u64 ce_keep(u64 mine, u64 other, bool keepSmall) {
    bool less = mine < other;
    u64 mn = less ? mine : other;
    u64 mx = less ? other : mine;
    return keepSmall ? mn : mx;
}

// One block per (batch, variant), 1024 threads, 4 elements/thread in registers.
// Hybrid bitonic sort: reg-local (j=1,2), shfl (j=4..128), LDS (j>=256).
__global__ __launch_bounds__(1024) void order_kernel(const float* __restrict__ x,
                                                     int* __restrict__ order) {
    const int b = blockIdx.x >> 1;
    const int v = blockIdx.x & 1;
    const int t = threadIdx.x;

    __shared__ u64 keys[NPTS];       // 32 KB
    __shared__ float red[16 * 6];

    const float* xb = x + (size_t)b * NPTS * 3;

    // Load this thread's 4 points (48 contiguous bytes) as 3x float4.
    float4 q0 = *(const float4*)(xb + 12 * t);
    float4 q1 = *(const float4*)(xb + 12 * t + 4);
    float4 q2 = *(const float4*)(xb + 12 * t + 8);
    float px[4] = {q0.x, q0.w, q1.z, q2.y};
    float py[4] = {q0.y, q1.x, q1.w, q2.z};
    float pz[4] = {q0.z, q1.y, q2.x, q2.w};

    // Per-batch min/max reduction.
    float mnx = 1e30f, mny = 1e30f, mnz = 1e30f;
    float mxx = -1e30f, mxy = -1e30f, mxz = -1e30f;
    #pragma unroll
    for (int r = 0; r < 4; ++r) {
        mnx = fminf(mnx, px[r]); mxx = fmaxf(mxx, px[r]);
        mny = fminf(mny, py[r]); mxy = fmaxf(mxy, py[r]);
        mnz = fminf(mnz, pz[r]); mxz = fmaxf(mxz, pz[r]);
    }
    #pragma unroll
    for (int off = 32; off > 0; off >>= 1) {
        mnx = fminf(mnx, __shfl_xor(mnx, off));
        mny = fminf(mny, __shfl_xor(mny, off));
        mnz = fminf(mnz, __shfl_xor(mnz, off));
        mxx = fmaxf(mxx, __shfl_xor(mxx, off));
        mxy = fmaxf(mxy, __shfl_xor(mxy, off));
        mxz = fmaxf(mxz, __shfl_xor(mxz, off));
    }
    int wave = t >> 6;
    if ((t & 63) == 0) {
        red[wave*6+0] = mnx; red[wave*6+1] = mny; red[wave*6+2] = mnz;
        red[wave*6+3] = mxx; red[wave*6+4] = mxy; red[wave*6+5] = mxz;
    }
    __syncthreads();
    if (t == 0) {
        for (int w = 1; w < 16; ++w) {
            mnx = fminf(mnx, red[w*6+0]); mny = fminf(mny, red[w*6+1]);
            mnz = fminf(mnz, red[w*6+2]); mxx = fmaxf(mxx, red[w*6+3]);
            mxy = fmaxf(mxy, red[w*6+4]); mxz = fmaxf(mxz, red[w*6+5]);
        }
        red[0] = mnx; red[1] = mny; red[2] = mnz;
        red[3] = mxx; red[4] = mxy; red[5] = mxz;
    }
    __syncthreads();
    mnx = red[0]; mny = red[1]; mnz = red[2];
    const float spx = fmaxf(red[3] - mnx, 1e-6f);
    const float spy = fmaxf(red[4] - mny, 1e-6f);
    const float spz = fmaxf(red[5] - mnz, 1e-6f);

    // Quantize + Hilbert code -> 64-bit stable key in registers.
    u64 e[4];
    #pragma unroll
    for (int r = 0; r < 4; ++r) {
        int n = 4 * t + r;
        float gx = fminf(fmaxf(((px[r] - mnx) / spx) * 255.0f, 0.0f), 255.0f);
        float gy = fminf(fmaxf(((py[r] - mny) / spy) * 255.0f, 0.0f), 255.0f);
        float gz = fminf(fmaxf(((pz[r] - mnz) / spz) * 255.0f, 0.0f), 255.0f);
        uint32_t ix = (uint32_t)(int)gx;
        uint32_t iy = (uint32_t)(int)gy;
        uint32_t iz = (uint32_t)(int)gz;
        uint32_t a0 = v ? iz : ix;
        uint32_t a2 = v ? ix : iz;
        uint32_t code = hilbert3(a0, iy, a2);
        e[r] = ((u64)code << 12) | (u64)n;
    }

    // Hybrid bitonic sort, ascending, element i = 4*t + r.
    for (int k = 2; k <= NPTS; k <<= 1) {
        for (int j = k >> 1; j > 0; j >>= 1) {
            if (j >= 256) {
                __syncthreads();
                #pragma unroll
                for (int r = 0; r < 4; ++r) keys[4*t + r] = e[r];
                __syncthreads();
                #pragma unroll
                for (int r = 0; r < 4; ++r) {
                    int i = 4*t + r;
                    u64 other = keys[i ^ j];
                    bool keepSmall = (((i & j) == 0) == ((i & k) == 0));
                    e[r] = ce_keep(e[r], other, keepSmall);
                }
            } else if (j >= 4) {
                int lm = j >> 2;
                #pragma unroll
                for (int r = 0; r < 4; ++r) {
                    int i = 4*t + r;
                    u64 other = shflx64(e[r], lm);
                    bool keepSmall = (((i & j) == 0) == ((i & k) == 0));
                    e[r] = ce_keep(e[r], other, keepSmall);
                }
            } else {
                #pragma unroll
                for (int r = 0; r < 4; ++r) {
                    if ((r & j) == 0) {
                        int i = 4*t + r;
                        bool asc = ((i & k) == 0);
                        int rp = r | j;
                        u64 a = e[r], c = e[rp];
                        bool less = a < c;
                        u64 mn = less ? a : c;
                        u64 mx = less ? c : a;
                        e[r]  = asc ? mn : mx;
                        e[rp] = asc ? mx : mn;
                    }
                }
            }
        }
    }

    // Write order: idx is low 12 bits.
    int* ob = order + (((b << 1) | v) << 12);
    int4 o4;
    o4.x = (int)(e[0] & 0xFFFull);
    o4.y = (int)(e[1] & 0xFFFull);
    o4.z = (int)(e[2] & 0xFFFull);
    o4.w = (int)(e[3] & 0xFFFull);
    *(int4*)(ob + 4 * t) = o4;
}

// Grid-stride over float4 output groups. out[b][nn][d] with nn<4096 -> variant h,
// nn>=4096 -> variant t. Coeffs staged in LDS.
__global__ __launch_bounds__(256) void token_kernel(const float* __restrict__ x,
                                                    const float* __restrict__ W,
                                                    const float* __restrict__ bias,
                                                    const float* __restrict__ gamma,
                                                    const float* __restrict__ beta,
                                                    const int* __restrict__ order,
                                                    float* __restrict__ out) {
    __shared__ __align__(16) float sW0[2][DIM];
    __shared__ __align__(16) float sW1[2][DIM];
    __shared__ __align__(16) float sW2[2][DIM];
    __shared__ __align__(16) float sC[2][DIM];
    for (int i = threadIdx.x; i < 2 * DIM; i += 256) {
        int v = i / DIM;
        int d = i - v * DIM;
        float g = gamma[i];
        sW0[v][d] = g * W[d*3+0];
        sW1[v][d] = g * W[d*3+1];
        sW2[v][d] = g * W[d*3+2];
        sC[v][d]  = g * bias[d] + beta[i];
    }
    __syncthreads();

    const int total = BATCH * NTOK * F4PT;   // 12,582,912
    const int stride = gridDim.x * blockDim.x;
    for (int g4 = blockIdx.x * blockDim.x + threadIdx.x; g4 < total; g4 += stride) {
        int token = g4 / F4PT;
        int grp = g4 - token * F4PT;
        int b = token >> 13;           // / NTOK
        int nn = token & (NTOK - 1);
        int v = nn >> 12;              // / NPTS
        int n = nn & (NPTS - 1);
        int idx = order[(((b << 1) | v) << 12) + n];
        const float* p = x + (size_t)(b * NPTS + idx) * 3;
        float px = p[0], py = p[1], pz = p[2];
        int d0 = grp << 2;
        float4 w0 = *(const float4*)&sW0[v][d0];
        float4 w1 = *(const float4*)&sW1[v][d0];
        float4 w2 = *(const float4*)&sW2[v][d0];
        float4 c  = *(const float4*)&sC[v][d0];
        float4 o;
        o.x = px*w0.x + py*w1.x + pz*w2.x + c.x;
        o.y = px*w0.y + py*w1.y + pz*w2.y + c.y;
        o.z = px*w0.z + py*w1.z + pz*w2.z + c.z;
        o.w = px*w0.w + py*w1.w + pz*w2.w + c.w;
        reinterpret_cast<float4*>(out)[g4] = o;
    }
}

extern "C" void kernel_launch(void* const* d_in, const int* in_sizes, int n_in,
                              void* d_out, int out_size, void* d_ws, size_t ws_size,
                              hipStream_t stream) {
    const float* x     = (const float*)d_in[0];
    const float* W     = (const float*)d_in[1];
    const float* bias  = (const float*)d_in[2];
    const float* gamma = (const float*)d_in[3];
    const float* beta  = (const float*)d_in[4];
    int* order = (int*)d_ws;   // 16*2*4096 int32 = 512 KB

    hipLaunchKernelGGL(order_kernel, dim3(BATCH * 2), dim3(1024), 0, stream, x, order);
    hipLaunchKernelGGL(token_kernel, dim3(2048), dim3(256), 0, stream,
                       x, W, bias, gamma, beta, order, (float*)d_out);
}

// Round 3
// 67.653 us; speedup vs baseline: 2.2640x; 1.2782x over previous
//
#include <hip/hip_runtime.h>
#include <stdint.h>

#define BATCH 16
#define NPTS 4096
#define DIM 384
#define NTOK (2*NPTS)
#define F4PT (DIM/4)   // 96 float4 groups per token

typedef unsigned long long u64;

struct alignas(16) u64x2 { u64 a, b; };

// Exact port of the reference Skilling transform (bits=8, ndim=3).
__device__ __forceinline__ uint32_t hilbert3(uint32_t x0, uint32_t x1, uint32_t x2) {
    #pragma unroll
    for (uint32_t q = 128; q > 1; q >>= 1) {
        uint32_t pm = q - 1;
        if (x0 & q) x0 ^= pm;
        uint32_t t = (x0 ^ x1) & pm;
        if (x1 & q) { x0 ^= pm; } else { x0 ^= t; x1 ^= t; }
        t = (x0 ^ x2) & pm;
        if (x2 & q) { x0 ^= pm; } else { x0 ^= t; x2 ^= t; }
    }
    x1 ^= x0;
    x2 ^= x1;
    uint32_t t = 0;
    #pragma unroll
    for (uint32_t q = 128; q > 1; q >>= 1) { if (x2 & q) t ^= (q - 1); }
    x0 ^= t; x1 ^= t; x2 ^= t;
    uint32_t h = 0;
    #pragma unroll
    for (int bp = 7; bp >= 0; --bp) {
        h = (h << 1) | ((x0 >> bp) & 1u);
        h = (h << 1) | ((x1 >> bp) & 1u);
        h = (h << 1) | ((x2 >> bp) & 1u);
    }
    return h;
}

__device__ __forceinline__ u64 shflx64(u64 v, int mask) {
    int lo = __shfl_xor((int)(uint32_t)v, mask);
    int hi = __shfl_xor((int)(uint32_t)(v >> 32), mask);
    return ((u64)(uint32_t)hi << 32) | (uint32_t)lo;
}

__device__ __forceinline__ u64 ce_keep(u64 mine, u64 other, bool keepSmall) {
    bool less = mine < other;
    u64 mn = less ? mine : other;
    u64 mx = less ? other : mine;
    return keepSmall ? mn : mx;
}

// K1: block = (b, v, half). Full bitonic network k=2..2048 on this block's
// 2048-element half (global-index direction bit => half0 asc, half1 desc).
// 1024 threads x 2 elements {2t, 2t+1}. Writes u64 keys to ws.
__global__ __launch_bounds__(1024) void order_local_kernel(const float* __restrict__ x,
                                                           u64* __restrict__ keys_ws) {
    const int b = blockIdx.x >> 2;
    const int v = (blockIdx.x >> 1) & 1;
    const int c = blockIdx.x & 1;          // half
    const int t = threadIdx.x;
    const int cb = c << 11;                // chunk base (0 or 2048)

    __shared__ __align__(16) u64 sk[2048];   // 16 KB
    __shared__ float red[16 * 6];

    const float* xb = x + (size_t)b * NPTS * 3;

    // --- per-batch min/max over ALL 4096 points (4 pts/thread) ---
    float4 q0 = *(const float4*)(xb + 12 * t);
    float4 q1 = *(const float4*)(xb + 12 * t + 4);
    float4 q2 = *(const float4*)(xb + 12 * t + 8);
    float px[4] = {q0.x, q0.w, q1.z, q2.y};
    float py[4] = {q0.y, q1.x, q1.w, q2.z};
    float pz[4] = {q0.z, q1.y, q2.x, q2.w};

    float mnx = 1e30f, mny = 1e30f, mnz = 1e30f;
    float mxx = -1e30f, mxy = -1e30f, mxz = -1e30f;
    #pragma unroll
    for (int r = 0; r < 4; ++r) {
        mnx = fminf(mnx, px[r]); mxx = fmaxf(mxx, px[r]);
        mny = fminf(mny, py[r]); mxy = fmaxf(mxy, py[r]);
        mnz = fminf(mnz, pz[r]); mxz = fmaxf(mxz, pz[r]);
    }
    #pragma unroll
    for (int off = 32; off > 0; off >>= 1) {
        mnx = fminf(mnx, __shfl_xor(mnx, off));
        mny = fminf(mny, __shfl_xor(mny, off));
        mnz = fminf(mnz, __shfl_xor(mnz, off));
        mxx = fmaxf(mxx, __shfl_xor(mxx, off));
        mxy = fmaxf(mxy, __shfl_xor(mxy, off));
        mxz = fmaxf(mxz, __shfl_xor(mxz, off));
    }
    int wave = t >> 6;
    if ((t & 63) == 0) {
        red[wave*6+0] = mnx; red[wave*6+1] = mny; red[wave*6+2] = mnz;
        red[wave*6+3] = mxx; red[wave*6+4] = mxy; red[wave*6+5] = mxz;
    }
    __syncthreads();
    if (t == 0) {
        for (int w = 1; w < 16; ++w) {
            mnx = fminf(mnx, red[w*6+0]); mny = fminf(mny, red[w*6+1]);
            mnz = fminf(mnz, red[w*6+2]); mxx = fmaxf(mxx, red[w*6+3]);
            mxy = fmaxf(mxy, red[w*6+4]); mxz = fmaxf(mxz, red[w*6+5]);
        }
        red[0] = mnx; red[1] = mny; red[2] = mnz;
        red[3] = mxx; red[4] = mxy; red[5] = mxz;
    }
    __syncthreads();
    mnx = red[0]; mny = red[1]; mnz = red[2];
    const float spx = fmaxf(red[3] - mnx, 1e-6f);
    const float spy = fmaxf(red[4] - mny, 1e-6f);
    const float spz = fmaxf(red[5] - mnz, 1e-6f);

    // --- own 2 points -> keys (key = code<<12 | idx, stable) ---
    u64 e0, e1;
    {
        const int n0 = cb + 2 * t;
        #pragma unroll
        for (int r = 0; r < 2; ++r) {
            int n = n0 + r;
            float ppx = xb[n*3+0], ppy = xb[n*3+1], ppz = xb[n*3+2];
            float gx = fminf(fmaxf(((ppx - mnx) / spx) * 255.0f, 0.0f), 255.0f);
            float gy = fminf(fmaxf(((ppy - mny) / spy) * 255.0f, 0.0f), 255.0f);
            float gz = fminf(fmaxf(((ppz - mnz) / spz) * 255.0f, 0.0f), 255.0f);
            uint32_t ix = (uint32_t)(int)gx;
            uint32_t iy = (uint32_t)(int)gy;
            uint32_t iz = (uint32_t)(int)gz;
            uint32_t a0 = v ? iz : ix;
            uint32_t a2 = v ? ix : iz;
            uint32_t code = hilbert3(a0, iy, a2);
            u64 key = ((u64)code << 12) | (u64)n;
            if (r == 0) e0 = key; else e1 = key;
        }
    }

    const int gi0 = cb + 2 * t;   // global position of e0 (e1 = gi0+1)

    // --- bitonic network k=2..2048 (direction from global index) ---
    for (int k = 2; k <= 2048; k <<= 1) {
        for (int j = k >> 1; j > 0; j >>= 1) {
            if (j == 1) {
                bool asc = ((gi0 & k) == 0);
                bool less = e0 < e1;
                u64 mn = less ? e0 : e1;
                u64 mx = less ? e1 : e0;
                e0 = asc ? mn : mx;
                e1 = asc ? mx : mn;
            } else if (j <= 64) {
                int lm = j >> 1;
                bool ks = (((gi0 & j) == 0) == ((gi0 & k) == 0));
                e0 = ce_keep(e0, shflx64(e0, lm), ks);
                e1 = ce_keep(e1, shflx64(e1, lm), ks);
            } else {
                __syncthreads();
                *(u64x2*)&sk[2*t] = {e0, e1};
                __syncthreads();
                int tp = t ^ (j >> 1);
                u64x2 o = *(const u64x2*)&sk[2*tp];
                bool ks = (((gi0 & j) == 0) == ((gi0 & k) == 0));
                e0 = ce_keep(e0, o.a, ks);
                e1 = ce_keep(e1, o.b, ks);
            }
        }
    }

    u64* kb = keys_ws + (((b << 1) | v) << 12);
    *(u64x2*)&kb[cb + 2*t] = {e0, e1};
}

// K2: k=4096 merge. Read own half + partner half (pre-merge values), do the
// j=2048 CE in registers, then local j=1024..1 merge, write order indices.
__global__ __launch_bounds__(1024) void order_merge_kernel(const u64* __restrict__ keys_ws,
                                                           int* __restrict__ order) {
    const int b = blockIdx.x >> 2;
    const int v = (blockIdx.x >> 1) & 1;
    const int c = blockIdx.x & 1;
    const int t = threadIdx.x;
    const int cb = c << 11;

    __shared__ __align__(16) u64 sk[2048];

    const u64* kb = keys_ws + (((b << 1) | v) << 12);
    u64x2 own  = *(const u64x2*)&kb[cb + 2*t];
    u64x2 part = *(const u64x2*)&kb[(cb ^ 2048) + 2*t];

    // j=2048 CE: half0 keeps min, half1 keeps max (final sort ascending).
    bool ks0 = (c == 0);
    u64 e0 = ce_keep(own.a, part.a, ks0);
    u64 e1 = ce_keep(own.b, part.b, ks0);

    const int gi0 = cb + 2 * t;

    // local merge, all ascending (k=4096)
    #pragma unroll
    for (int j = 1024; j > 0; j >>= 1) {
        if (j == 1) {
            bool less = e0 < e1;
            u64 mn = less ? e0 : e1;
            u64 mx = less ? e1 : e0;
            e0 = mn; e1 = mx;
        } else if (j <= 64) {
            int lm = j >> 1;
            bool ks = ((gi0 & j) == 0);
            e0 = ce_keep(e0, shflx64(e0, lm), ks);
            e1 = ce_keep(e1, shflx64(e1, lm), ks);
        } else {
            __syncthreads();
            *(u64x2*)&sk[2*t] = {e0, e1};
            __syncthreads();
            int tp = t ^ (j >> 1);
            u64x2 o = *(const u64x2*)&sk[2*tp];
            bool ks = ((gi0 & j) == 0);
            e0 = ce_keep(e0, o.a, ks);
            e1 = ce_keep(e1, o.b, ks);
        }
    }

    int* ob = order + (((b << 1) | v) << 12);
    int2 o2;
    o2.x = (int)(e0 & 0xFFFull);
    o2.y = (int)(e1 & 0xFFFull);
    *(int2*)&ob[cb + 2*t] = o2;
}

// Grid-stride over float4 output groups. out[b][nn][d] with nn<4096 -> variant h,
// nn>=4096 -> variant t. Coeffs staged in LDS.
__global__ __launch_bounds__(256) void token_kernel(const float* __restrict__ x,
                                                    const float* __restrict__ W,
                                                    const float* __restrict__ bias,
                                                    const float* __restrict__ gamma,
                                                    const float* __restrict__ beta,
                                                    const int* __restrict__ order,
                                                    float* __restrict__ out) {
    __shared__ __align__(16) float sW0[2][DIM];
    __shared__ __align__(16) float sW1[2][DIM];
    __shared__ __align__(16) float sW2[2][DIM];
    __shared__ __align__(16) float sC[2][DIM];
    for (int i = threadIdx.x; i < 2 * DIM; i += 256) {
        int v = i / DIM;
        int d = i - v * DIM;
        float g = gamma[i];
        sW0[v][d] = g * W[d*3+0];
        sW1[v][d] = g * W[d*3+1];
        sW2[v][d] = g * W[d*3+2];
        sC[v][d]  = g * bias[d] + beta[i];
    }
    __syncthreads();

    const int total = BATCH * NTOK * F4PT;   // 12,582,912
    const int stride = gridDim.x * blockDim.x;
    for (int g4 = blockIdx.x * blockDim.x + threadIdx.x; g4 < total; g4 += stride) {
        int token = g4 / F4PT;
        int grp = g4 - token * F4PT;
        int b = token >> 13;           // / NTOK
        int nn = token & (NTOK - 1);
        int v = nn >> 12;              // / NPTS
        int n = nn & (NPTS - 1);
        int idx = order[(((b << 1) | v) << 12) + n];
        const float* p = x + (size_t)(b * NPTS + idx) * 3;
        float px = p[0], py = p[1], pz = p[2];
        int d0 = grp << 2;
        float4 w0 = *(const float4*)&sW0[v][d0];
        float4 w1 = *(const float4*)&sW1[v][d0];
        float4 w2 = *(const float4*)&sW2[v][d0];
        float4 c  = *(const float4*)&sC[v][d0];
        float4 o;
        o.x = px*w0.x + py*w1.x + pz*w2.x + c.x;
        o.y = px*w0.y + py*w1.y + pz*w2.y + c.y;
        o.z = px*w0.z + py*w1.z + pz*w2.z + c.z;
        o.w = px*w0.w + py*w1.w + pz*w2.w + c.w;
        reinterpret_cast<float4*>(out)[g4] = o;
    }
}

extern "C" void kernel_launch(void* const* d_in, const int* in_sizes, int n_in,
                              void* d_out, int out_size, void* d_ws, size_t ws_size,
                              hipStream_t stream) {
    const float* x     = (const float*)d_in[0];
    const float* W     = (const float*)d_in[1];
    const float* bias  = (const float*)d_in[2];
    const float* gamma = (const float*)d_in[3];
    const float* beta  = (const float*)d_in[4];

    u64* keys_ws = (u64*)d_ws;                          // 32*4096*8 = 1 MB
    int* order   = (int*)((char*)d_ws + (32*4096*8));   // 512 KB

    hipLaunchKernelGGL(order_local_kernel, dim3(BATCH * 4), dim3(1024), 0, stream, x, keys_ws);
    hipLaunchKernelGGL(order_merge_kernel, dim3(BATCH * 4), dim3(1024), 0, stream, keys_ws, order);
    hipLaunchKernelGGL(token_kernel, dim3(2048), dim3(256), 0, stream,
                       x, W, bias, gamma, beta, order, (float*)d_out);
}